// Round 1
// baseline (18.978 us; speedup 1.0000x reference)
//
#include <hip/hip_runtime.h>

// EulerMisorientation3D — fused elementwise + mean reduction.
// N voxels; x,x_hat are (3, D, H, W) float32 channel-major planes.
// Per voxel: g, g_hat from Bunge Euler angles (phi1=2pi*x0, Phi=pi*x1, phi2=2pi*x2),
// tr = sum_i g_hat[ii] * inv(g)[ii]  (inv diag via adjugate/det),
// mis = acos(0.5*(tr-1))^2, output = mean(mis).
//
// v_sin_f32 / v_cos_f32 take REVOLUTIONS: sin(2*pi*u) == __builtin_amdgcn_sinf(u).
// So phi1 rev = x0, Phi rev = 0.5*x1, phi2 rev = x2 — no range reduction needed
// (inputs are in [-0.2, 1.2]).

#define NTHR 256

__device__ __forceinline__ float wave_block_reduce(float v, float* lds, int tid) {
    // wave64 butterfly then cross-wave via LDS (256 threads = 4 waves)
    #pragma unroll
    for (int off = 32; off > 0; off >>= 1) v += __shfl_down(v, off, 64);
    if ((tid & 63) == 0) lds[tid >> 6] = v;
    __syncthreads();
    float r = 0.f;
    if (tid == 0) r = lds[0] + lds[1] + lds[2] + lds[3];
    return r;
}

__global__ __launch_bounds__(NTHR)
void euler_mis_partial(const float* __restrict__ x, const float* __restrict__ xh,
                       float* __restrict__ partials, int nvox) {
    const int tid = threadIdx.x;
    const int gid = blockIdx.x * NTHR + tid;     // float4 index within a plane

    const float4 a0 = reinterpret_cast<const float4*>(x)[gid];
    const float4 a1 = reinterpret_cast<const float4*>(x + nvox)[gid];
    const float4 a2 = reinterpret_cast<const float4*>(x + 2 * (size_t)nvox)[gid];
    const float4 b0 = reinterpret_cast<const float4*>(xh)[gid];
    const float4 b1 = reinterpret_cast<const float4*>(xh + nvox)[gid];
    const float4 b2 = reinterpret_cast<const float4*>(xh + 2 * (size_t)nvox)[gid];

    const float u0[4] = {a0.x, a0.y, a0.z, a0.w};
    const float u1[4] = {a1.x, a1.y, a1.z, a1.w};
    const float u2[4] = {a2.x, a2.y, a2.z, a2.w};
    const float v0[4] = {b0.x, b0.y, b0.z, b0.w};
    const float v1[4] = {b1.x, b1.y, b1.z, b1.w};
    const float v2[4] = {b2.x, b2.y, b2.z, b2.w};

    float acc = 0.f;
    #pragma unroll
    for (int j = 0; j < 4; ++j) {
        // hardware trig in revolutions
        const float s1 = __builtin_amdgcn_sinf(u0[j]);
        const float c1 = __builtin_amdgcn_cosf(u0[j]);
        const float sP = __builtin_amdgcn_sinf(0.5f * u1[j]);
        const float cP = __builtin_amdgcn_cosf(0.5f * u1[j]);
        const float s2 = __builtin_amdgcn_sinf(u2[j]);
        const float c2 = __builtin_amdgcn_cosf(u2[j]);

        const float t1 = __builtin_amdgcn_sinf(v0[j]);
        const float d1 = __builtin_amdgcn_cosf(v0[j]);
        const float tP = __builtin_amdgcn_sinf(0.5f * v1[j]);
        const float dP = __builtin_amdgcn_cosf(0.5f * v1[j]);
        const float t2 = __builtin_amdgcn_sinf(v2[j]);
        const float d2 = __builtin_amdgcn_cosf(v2[j]);

        // full g (needed for adjugate diag of inverse)
        const float g00 = c1 * c2 - s1 * s2 * cP;
        const float g01 = s1 * c2 + c1 * s2 * cP;
        const float g02 = s2 * sP;
        const float g10 = -c1 * s2 - s1 * c2 * cP;
        const float g11 = -s1 * s2 + c1 * c2 * cP;
        const float g12 = c2 * sP;
        const float g20 = s1 * sP;
        const float g21 = -c1 * sP;
        const float g22 = cP;

        // diag of inv(g) = cofactor_ii / det
        const float cof00 = g11 * g22 - g12 * g21;
        const float cof11 = g00 * g22 - g02 * g20;
        const float cof22 = g00 * g11 - g01 * g10;
        const float det = g00 * cof00
                        - g01 * (g10 * g22 - g12 * g20)
                        + g02 * (g10 * g21 - g11 * g20);
        const float invdet = 1.0f / det;

        // only the diagonal of g_hat is needed
        const float h00 = d1 * d2 - t1 * t2 * dP;
        const float h11 = -t1 * t2 + d1 * d2 * dP;
        const float h22 = dP;

        const float tr = (h00 * cof00 + h11 * cof11 + h22 * cof22) * invdet;
        float arg = 0.5f * (tr - 1.0f);
        arg = fminf(1.0f, fmaxf(-1.0f, arg));
        const float m = acosf(arg);
        acc += m * m;
    }

    __shared__ float lds[4];
    const float bsum = wave_block_reduce(acc, lds, tid);
    if (tid == 0) partials[blockIdx.x] = bsum;
}

__global__ __launch_bounds__(NTHR)
void euler_mis_finalize(const float* __restrict__ partials, int nblk,
                        float* __restrict__ out, float inv_n) {
    const int tid = threadIdx.x;
    float s = 0.f;
    for (int i = tid; i < nblk; i += NTHR) s += partials[i];
    __shared__ float lds[4];
    const float tot = wave_block_reduce(s, lds, tid);
    if (tid == 0) out[0] = tot * inv_n;
}

extern "C" void kernel_launch(void* const* d_in, const int* in_sizes, int n_in,
                              void* d_out, int out_size, void* d_ws, size_t ws_size,
                              hipStream_t stream) {
    const float* x  = (const float*)d_in[0];
    const float* xh = (const float*)d_in[1];
    float* out = (float*)d_out;
    float* partials = (float*)d_ws;

    const int nvox = in_sizes[0] / 3;          // 128^3 = 2,097,152
    const int nvec = nvox / 4;                 // float4 groups per plane
    const int nblk = (nvec + NTHR - 1) / NTHR; // 2048

    euler_mis_partial<<<nblk, NTHR, 0, stream>>>(x, xh, partials, nvox);
    euler_mis_finalize<<<1, NTHR, 0, stream>>>(partials, nblk, out, 1.0f / (float)nvox);
}